// Round 5
// baseline (689.160 us; speedup 1.0000x reference)
//
#include <hip/hip_runtime.h>
#include <hip/hip_bf16.h>

// AttentionAggregator: fused one-pass kernel, round 5.
// Changes vs R4 (288us; ~74us of exposed HBM latency):
//  - Explicit software prefetch of the next pair's x/mask, placed AFTER the
//    current pair's x registers die. To make them die early, pooling/gather
//    candidates (pl, gth; 16 regs) are computed right after softmax, then the
//    x registers (32) are reused for the prefetch. The classifier (~1200 cyc
//    of issue per pair) then covers the ~900 cyc HBM latency.
//  - Loop-top asm "memory" clobber kept (stops LICM of the LDS w2 tile into
//    128 spilled regs, R3's failure); the prefetch sits before it in program
//    order so it still overlaps the next iteration.
//  - Last iteration skips prefetch via a wave-uniform branch (a pointer clamp
//    would re-fetch ~139MB from HBM = +22us).
//  - Softmax normalization via v_rcp (1e-6 rel err, invisible at bf16 floor).

namespace {
constexpr float kEps = 1e-5f;
constexpr float kLn3 = 1.0986122886681098f;  // ln(3)
}

__device__ __forceinline__ float lane_bcast(float v, int srclane) {
    return __uint_as_float(__builtin_amdgcn_readlane(__float_as_uint(v), srclane));
}

template <int CTRL>
__device__ __forceinline__ float dpp_add(float x) {
    int s = __builtin_amdgcn_update_dpp(0, __float_as_int(x), CTRL, 0xF, 0xF, true);
    return x + __int_as_float(s);
}

// Full 64-lane sum on the VALU pipe; total lands in lane 63.
__device__ __forceinline__ float dpp_sum63(float x) {
    x = dpp_add<0x111>(x);  // row_shr:1
    x = dpp_add<0x112>(x);  // row_shr:2
    x = dpp_add<0x114>(x);  // row_shr:4
    x = dpp_add<0x118>(x);  // row_shr:8
    x = dpp_add<0x142>(x);  // row_bcast:15
    x = dpp_add<0x143>(x);  // row_bcast:31
    return x;
}

__device__ __forceinline__ float dot4(float4 a, float4 b) {
    return fmaf(a.w, b.w, fmaf(a.z, b.z, fmaf(a.y, b.y, a.x * b.x)));
}

// tanh(x) = 1 - 2/(e^{2x}+1); ~1e-6 rel err, saturates correctly.
__device__ __forceinline__ float fast_tanh(float x) {
    const float t = __expf(2.0f * x);
    return fmaf(-2.0f, __builtin_amdgcn_rcpf(t + 1.0f), 1.0f);
}

__global__ __launch_bounds__(256, 4) void agg_fused(
    const float* __restrict__ x, const float* __restrict__ mask,
    const float* __restrict__ attn_w, const float* __restrict__ attn_b,
    const float* __restrict__ w1, const float* __restrict__ b1,
    const float* __restrict__ g1, const float* __restrict__ be1,
    const float* __restrict__ m1, const float* __restrict__ v1,
    const float* __restrict__ w2, const float* __restrict__ b2,
    const float* __restrict__ g2, const float* __restrict__ be2,
    const float* __restrict__ m2, const float* __restrict__ v2,
    const float* __restrict__ w3, const float* __restrict__ b3,
    float* __restrict__ out_ret, float* __restrict__ out_w,
    float* __restrict__ out_cls, int bpw)
{
    // w2 tile, slot-XOR swizzled: chunk (j, c) lives at w2s4[j*32 + (c^(j&7))]
    // -> a wave-wide ds_read_b128 of one chunk column hits the structural
    // 8-pass minimum with zero bank conflicts.
    __shared__ float4 w2s4[64 * 32];

    const int tid  = threadIdx.x;
    const int lane = tid & 63;
    const int wid  = blockIdx.x * 4 + (tid >> 6);

    // ---- stage w2 into LDS (once per block, coalesced) ----
    {
        const float4* w2v = reinterpret_cast<const float4*>(w2);
#pragma unroll
        for (int p = 0; p < 8; ++p) {
            const int idx = tid + p * 256;           // = j*32 + c
            const int j = idx >> 5, c = idx & 31;
            w2s4[j * 32 + (c ^ (j & 7))] = w2v[idx];
        }
    }
    __syncthreads();

    // ---- loop-invariant per-lane parameters (BN folded to fma consts) ----
    const float4 aw  = *reinterpret_cast<const float4*>(attn_w + lane * 4);
    const float  ab  = attn_b[0];
    const float4 w1a = *reinterpret_cast<const float4*>(w1 + lane * 4);
    const float4 w1b = *reinterpret_cast<const float4*>(w1 + (lane + 64) * 4);
    const float  b1a = b1[lane], b1b = b1[lane + 64];
    const float  c1a = g1[lane] * (1.0f / sqrtf(v1[lane] + kEps));
    const float  c1b = g1[lane + 64] * (1.0f / sqrtf(v1[lane + 64] + kEps));
    const float  c0a = be1[lane] - m1[lane] * c1a;
    const float  c0b = be1[lane + 64] - m1[lane + 64] * c1b;
    const float  b2j = b2[lane];

    // head fold: cls = [ sum_j alpha_j*ReLU(pre_j) > thrp ]
    float alpha, thrp;
    {
        const float wdj = w3[64 + lane] - w3[lane];
        const float c12 = g2[lane] * (1.0f / sqrtf(v2[lane] + kEps));
        const float c02 = be2[lane] - m2[lane] * c12;
        alpha = wdj * c12;
        const float C = lane_bcast(dpp_sum63(wdj * c02), 63);
        thrp = kLn3 - (b3[1] - b3[0]) - C;
    }

    // 8 swizzled row base indices for this lane's w2 row (float4 units).
    int wofs[8];
#pragma unroll
    for (int m = 0; m < 8; ++m) wofs[m] = lane * 32 + (m ^ (lane & 7));

    const int b0 = wid * bpw;
    const float* xb = x    + (size_t)b0 * 1024 + lane * 4;
    const float* mb = mask + (size_t)b0 * 4;
    float*       rp = out_ret + (size_t)b0 * 256 + lane * 4;
    float*       wp = out_w   + (size_t)b0 * 4;
    float*       cp = out_cls + b0;

    // ---- prologue: load pair 0 ----
    float4 xu0 = *reinterpret_cast<const float4*>(xb + 0);
    float4 xu1 = *reinterpret_cast<const float4*>(xb + 256);
    float4 xu2 = *reinterpret_cast<const float4*>(xb + 512);
    float4 xu3 = *reinterpret_cast<const float4*>(xb + 768);
    float4 xv0 = *reinterpret_cast<const float4*>(xb + 1024);
    float4 xv1 = *reinterpret_cast<const float4*>(xb + 1280);
    float4 xv2 = *reinterpret_cast<const float4*>(xb + 1536);
    float4 xv3 = *reinterpret_cast<const float4*>(xb + 1792);
    float4 mku = *reinterpret_cast<const float4*>(mb);
    float4 mkv = *reinterpret_cast<const float4*>(mb + 4);

#pragma unroll 1
    for (int i = 0; i < bpw; i += 2) {
        // Compiler barrier: stops LICM of the loop-invariant LDS w2 reads
        // (R3's spill). The prefetch of this pair happened BEFORE this point
        // in program order (previous iteration), so overlap is preserved.
        asm volatile("" ::: "memory");

        // ---- phase 1: attention scores (8 independent DPP chains) ----
        float ru0 = dpp_sum63(dot4(xu0, aw));
        float ru1 = dpp_sum63(dot4(xu1, aw));
        float ru2 = dpp_sum63(dot4(xu2, aw));
        float ru3 = dpp_sum63(dot4(xu3, aw));
        float rv0 = dpp_sum63(dot4(xv0, aw));
        float rv1 = dpp_sum63(dot4(xv1, aw));
        float rv2 = dpp_sum63(dot4(xv2, aw));
        float rv3 = dpp_sum63(dot4(xv3, aw));
        const float au0 = fast_tanh(lane_bcast(ru0, 63) + ab) + mku.x;
        const float au1 = fast_tanh(lane_bcast(ru1, 63) + ab) + mku.y;
        const float au2 = fast_tanh(lane_bcast(ru2, 63) + ab) + mku.z;
        const float au3 = fast_tanh(lane_bcast(ru3, 63) + ab) + mku.w;
        const float av0 = fast_tanh(lane_bcast(rv0, 63) + ab) + mkv.x;
        const float av1 = fast_tanh(lane_bcast(rv1, 63) + ab) + mkv.y;
        const float av2 = fast_tanh(lane_bcast(rv2, 63) + ab) + mkv.z;
        const float av3 = fast_tanh(lane_bcast(rv3, 63) + ab) + mkv.w;

        // ---- softmax over 4 members, each batch ----
        const float umax = fmaxf(fmaxf(au0, au1), fmaxf(au2, au3));
        const float eu0 = __expf(au0 - umax), eu1 = __expf(au1 - umax);
        const float eu2 = __expf(au2 - umax), eu3 = __expf(au3 - umax);
        const float urs = __builtin_amdgcn_rcpf(((eu0 + eu1) + eu2) + eu3);
        const float wtu0 = eu0 * urs, wtu1 = eu1 * urs, wtu2 = eu2 * urs, wtu3 = eu3 * urs;

        const float vmax = fmaxf(fmaxf(av0, av1), fmaxf(av2, av3));
        const float ev0 = __expf(av0 - vmax), ev1 = __expf(av1 - vmax);
        const float ev2 = __expf(av2 - vmax), ev3 = __expf(av3 - vmax);
        const float vrs = __builtin_amdgcn_rcpf(((ev0 + ev1) + ev2) + ev3);
        const float wtv0 = ev0 * vrs, wtv1 = ev1 * vrs, wtv2 = ev2 * vrs, wtv3 = ev3 * vrs;

        // ---- phase 2: pooling + gather candidates (x registers die here) ----
        float4 plU, gthU, plV, gthV;
        {
            int midx = 0; float mval = wtu0;
            if (wtu1 > mval) { mval = wtu1; midx = 1; }
            if (wtu2 > mval) { mval = wtu2; midx = 2; }
            if (wtu3 > mval) { mval = wtu3; midx = 3; }
            const float4 g01 = (midx == 1) ? xu1 : xu0;
            const float4 g23 = (midx == 3) ? xu3 : xu2;
            gthU = (midx >= 2) ? g23 : g01;
            plU.x = fmaf(wtu3, xu3.x, fmaf(wtu2, xu2.x, fmaf(wtu1, xu1.x, wtu0 * xu0.x)));
            plU.y = fmaf(wtu3, xu3.y, fmaf(wtu2, xu2.y, fmaf(wtu1, xu1.y, wtu0 * xu0.y)));
            plU.z = fmaf(wtu3, xu3.z, fmaf(wtu2, xu2.z, fmaf(wtu1, xu1.z, wtu0 * xu0.z)));
            plU.w = fmaf(wtu3, xu3.w, fmaf(wtu2, xu2.w, fmaf(wtu1, xu1.w, wtu0 * xu0.w)));
        }
        {
            int midx = 0; float mval = wtv0;
            if (wtv1 > mval) { mval = wtv1; midx = 1; }
            if (wtv2 > mval) { mval = wtv2; midx = 2; }
            if (wtv3 > mval) { mval = wtv3; midx = 3; }
            const float4 g01 = (midx == 1) ? xv1 : xv0;
            const float4 g23 = (midx == 3) ? xv3 : xv2;
            gthV = (midx >= 2) ? g23 : g01;
            plV.x = fmaf(wtv3, xv3.x, fmaf(wtv2, xv2.x, fmaf(wtv1, xv1.x, wtv0 * xv0.x)));
            plV.y = fmaf(wtv3, xv3.y, fmaf(wtv2, xv2.y, fmaf(wtv1, xv1.y, wtv0 * xv0.y)));
            plV.z = fmaf(wtv3, xv3.z, fmaf(wtv2, xv2.z, fmaf(wtv1, xv1.z, wtv0 * xv0.z)));
            plV.w = fmaf(wtv3, xv3.w, fmaf(wtv2, xv2.w, fmaf(wtv1, xv1.w, wtv0 * xv0.w)));
        }

        // ---- phase 3: prefetch next pair into the (now dead) x registers.
        // Wave-uniform branch; classifier below (~1200 cyc issue) hides the
        // ~900 cyc HBM latency. ----
        if (i + 2 < bpw) {
            const float* xn = xb + (size_t)(i + 2) * 1024;
            const float* mn = mb + (size_t)(i + 2) * 4;
            xu0 = *reinterpret_cast<const float4*>(xn + 0);
            xu1 = *reinterpret_cast<const float4*>(xn + 256);
            xu2 = *reinterpret_cast<const float4*>(xn + 512);
            xu3 = *reinterpret_cast<const float4*>(xn + 768);
            xv0 = *reinterpret_cast<const float4*>(xn + 1024);
            xv1 = *reinterpret_cast<const float4*>(xn + 1280);
            xv2 = *reinterpret_cast<const float4*>(xn + 1536);
            xv3 = *reinterpret_cast<const float4*>(xn + 1792);
            mku = *reinterpret_cast<const float4*>(mn);
            mkv = *reinterpret_cast<const float4*>(mn + 4);
        }

        // ---- phase 4: classifier (layer1 -> layer2 matvec -> head) ----
        float pu = fmaf(wtu3, w1a.w, fmaf(wtu2, w1a.z, fmaf(wtu1, w1a.y, wtu0 * w1a.x))) + b1a;
        const float h1uA = fmaf(fmaxf(pu, 0.0f), c1a, c0a);
        pu = fmaf(wtu3, w1b.w, fmaf(wtu2, w1b.z, fmaf(wtu1, w1b.y, wtu0 * w1b.x))) + b1b;
        const float h1uB = fmaf(fmaxf(pu, 0.0f), c1b, c0b);
        float pv = fmaf(wtv3, w1a.w, fmaf(wtv2, w1a.z, fmaf(wtv1, w1a.y, wtv0 * w1a.x))) + b1a;
        const float h1vA = fmaf(fmaxf(pv, 0.0f), c1a, c0a);
        pv = fmaf(wtv3, w1b.w, fmaf(wtv2, w1b.z, fmaf(wtv1, w1b.y, wtv0 * w1b.x))) + b1b;
        const float h1vB = fmaf(fmaxf(pv, 0.0f), c1b, c0b);

        float accu0 = 0.0f, accu1 = 0.0f, accu2 = 0.0f, accu3 = 0.0f;
        float accv0 = 0.0f, accv1 = 0.0f, accv2 = 0.0f, accv3 = 0.0f;
#pragma unroll
        for (int c = 0; c < 32; ++c) {
            const float4 wv = w2s4[wofs[c & 7] + (c >> 3) * 8];
            const float srcU = (c < 16) ? h1uA : h1uB;
            const float srcV = (c < 16) ? h1vA : h1vB;
            const int l0 = (4 * c) & 63;
            accu0 = fmaf(lane_bcast(srcU, l0 + 0), wv.x, accu0);
            accu1 = fmaf(lane_bcast(srcU, l0 + 1), wv.y, accu1);
            accu2 = fmaf(lane_bcast(srcU, l0 + 2), wv.z, accu2);
            accu3 = fmaf(lane_bcast(srcU, l0 + 3), wv.w, accu3);
            accv0 = fmaf(lane_bcast(srcV, l0 + 0), wv.x, accv0);
            accv1 = fmaf(lane_bcast(srcV, l0 + 1), wv.y, accv1);
            accv2 = fmaf(lane_bcast(srcV, l0 + 2), wv.z, accv2);
            accv3 = fmaf(lane_bcast(srcV, l0 + 3), wv.w, accv3);
        }
        const float preU = ((accu0 + accu1) + (accu2 + accu3)) + b2j;
        const float preV = ((accv0 + accv1) + (accv2 + accv3)) + b2j;
        float dzu = dpp_sum63(alpha * fmaxf(preU, 0.0f));
        float dzv = dpp_sum63(alpha * fmaxf(preV, 0.0f));
        const int clsU = (lane_bcast(dzu, 63) > thrp) ? 1 : 0;
        const int clsV = (lane_bcast(dzv, 63) > thrp) ? 1 : 0;

        // ---- phase 5: select + store ----
        const float4 retU = (clsU == 1) ? gthU : plU;
        const float4 retV = (clsV == 1) ? gthV : plV;
        *reinterpret_cast<float4*>(rp + (size_t)i * 256)       = retU;
        *reinterpret_cast<float4*>(rp + (size_t)(i + 1) * 256) = retV;
        if (lane == 0) {
            *reinterpret_cast<float4*>(wp + (size_t)i * 4) =
                make_float4(wtu0, wtu1, wtu2, wtu3);
            *reinterpret_cast<float4*>(wp + (size_t)(i + 1) * 4) =
                make_float4(wtv0, wtv1, wtv2, wtv3);
            cp[i]     = (float)clsU;
            cp[i + 1] = (float)clsV;
        }
    }
}

extern "C" void kernel_launch(void* const* d_in, const int* in_sizes, int n_in,
                              void* d_out, int out_size, void* d_ws, size_t ws_size,
                              hipStream_t stream) {
    const float* x      = (const float*)d_in[0];
    const float* mask   = (const float*)d_in[1];
    const float* attn_w = (const float*)d_in[2];
    const float* attn_b = (const float*)d_in[3];
    const float* w1     = (const float*)d_in[4];
    const float* b1     = (const float*)d_in[5];
    const float* g1     = (const float*)d_in[6];
    const float* be1    = (const float*)d_in[7];
    const float* m1     = (const float*)d_in[8];
    const float* v1     = (const float*)d_in[9];
    const float* w2     = (const float*)d_in[10];
    const float* b2     = (const float*)d_in[11];
    const float* g2     = (const float*)d_in[12];
    const float* be2    = (const float*)d_in[13];
    const float* m2     = (const float*)d_in[14];
    const float* v2     = (const float*)d_in[15];
    const float* w3     = (const float*)d_in[16];
    const float* b3     = (const float*)d_in[17];

    float* out = (float*)d_out;
    float* out_ret = out;                         // [B, 256]
    float* out_w   = out + (size_t)262144 * 256;  // [B, 4, 1]
    float* out_cls = out_w + (size_t)262144 * 4;  // [B]

    const int threads = 256;                      // 4 waves/block
    const int blocks  = 4096;                     // 16384 waves total
    const int waves   = blocks * (threads / 64);
    const int bpw     = 262144 / waves;           // 16 batches/wave (8 pairs)

    agg_fused<<<blocks, threads, 0, stream>>>(
        x, mask, attn_w, attn_b, w1, b1, g1, be1, m1, v1,
        w2, b2, g2, be2, m2, v2, w3, b3,
        out_ret, out_w, out_cls, bpw);
}

// Round 6
// 638.475 us; speedup vs baseline: 1.0794x; 1.0794x over previous
//
#include <hip/hip_runtime.h>
#include <hip/hip_bf16.h>

// AttentionAggregator: fused one-pass kernel, round 6.
// R5 post-mortem: VGPR=64 + 1.2GB scratch writes = the LLVM GCN allocator
// CHOSE 8 waves/EU (64 regs) and spilled the loop body; launch_bounds' 2nd
// arg only sets a MINIMUM waves/EU. Fixes:
//  - amdgpu_waves_per_eu(4,4) pins occupancy: allocator gets 128 VGPRs and
//    cannot trade spills for 8-wave occupancy.
//  - Matvec h1 broadcast via wave-private LDS row (4 ds_write + 64 uniform
//    broadcast ds_read_b128) instead of 512 v_readlane -> per-pair VALU
//    ~1480 -> ~750 cyc, fewer live temps.
//  - out_w stored right after softmax so weight regs die before the matvec.
//  - R5's early-pooling + register prefetch kept (the latency fix was right;
//    only the spill killed it).

namespace {
constexpr float kEps = 1e-5f;
constexpr float kLn3 = 1.0986122886681098f;  // ln(3)
}

__device__ __forceinline__ float lane_bcast(float v, int srclane) {
    return __uint_as_float(__builtin_amdgcn_readlane(__float_as_uint(v), srclane));
}

template <int CTRL>
__device__ __forceinline__ float dpp_add(float x) {
    int s = __builtin_amdgcn_update_dpp(0, __float_as_int(x), CTRL, 0xF, 0xF, true);
    return x + __int_as_float(s);
}

// Full 64-lane sum on the VALU pipe; total lands in lane 63.
__device__ __forceinline__ float dpp_sum63(float x) {
    x = dpp_add<0x111>(x);  // row_shr:1
    x = dpp_add<0x112>(x);  // row_shr:2
    x = dpp_add<0x114>(x);  // row_shr:4
    x = dpp_add<0x118>(x);  // row_shr:8
    x = dpp_add<0x142>(x);  // row_bcast:15
    x = dpp_add<0x143>(x);  // row_bcast:31
    return x;
}

__device__ __forceinline__ float dot4(float4 a, float4 b) {
    return fmaf(a.w, b.w, fmaf(a.z, b.z, fmaf(a.y, b.y, a.x * b.x)));
}

// tanh(x) = 1 - 2/(e^{2x}+1); ~1e-6 rel err, saturates correctly.
__device__ __forceinline__ float fast_tanh(float x) {
    const float t = __expf(2.0f * x);
    return fmaf(-2.0f, __builtin_amdgcn_rcpf(t + 1.0f), 1.0f);
}

__global__ __launch_bounds__(256)
__attribute__((amdgpu_waves_per_eu(4, 4)))
void agg_fused(
    const float* __restrict__ x, const float* __restrict__ mask,
    const float* __restrict__ attn_w, const float* __restrict__ attn_b,
    const float* __restrict__ w1, const float* __restrict__ b1,
    const float* __restrict__ g1, const float* __restrict__ be1,
    const float* __restrict__ m1, const float* __restrict__ v1,
    const float* __restrict__ w2, const float* __restrict__ b2,
    const float* __restrict__ g2, const float* __restrict__ be2,
    const float* __restrict__ m2, const float* __restrict__ v2,
    const float* __restrict__ w3, const float* __restrict__ b3,
    float* __restrict__ out_ret, float* __restrict__ out_w,
    float* __restrict__ out_cls, int bpw)
{
    // w2 tile, slot-XOR swizzled: chunk (j, c) lives at w2s4[j*32 + (c^(j&7))].
    __shared__ float4 w2s4[64 * 32];
    // wave-private h1 broadcast rows: [wave][u/v][128]
    __shared__ float h1s[4][2][128];

    const int tid  = threadIdx.x;
    const int lane = tid & 63;
    const int wiw  = tid >> 6;
    const int wid  = blockIdx.x * 4 + wiw;

    // ---- stage w2 into LDS (once per block, coalesced) ----
    {
        const float4* w2v = reinterpret_cast<const float4*>(w2);
#pragma unroll
        for (int p = 0; p < 8; ++p) {
            const int idx = tid + p * 256;           // = j*32 + c
            const int j = idx >> 5, c = idx & 31;
            w2s4[j * 32 + (c ^ (j & 7))] = w2v[idx];
        }
    }
    __syncthreads();

    // ---- loop-invariant per-lane parameters (BN folded to fma consts) ----
    const float4 aw  = *reinterpret_cast<const float4*>(attn_w + lane * 4);
    const float  ab  = attn_b[0];
    const float4 w1a = *reinterpret_cast<const float4*>(w1 + lane * 4);
    const float4 w1b = *reinterpret_cast<const float4*>(w1 + (lane + 64) * 4);
    const float  b1a = b1[lane], b1b = b1[lane + 64];
    const float  c1a = g1[lane] * (1.0f / sqrtf(v1[lane] + kEps));
    const float  c1b = g1[lane + 64] * (1.0f / sqrtf(v1[lane + 64] + kEps));
    const float  c0a = be1[lane] - m1[lane] * c1a;
    const float  c0b = be1[lane + 64] - m1[lane + 64] * c1b;
    const float  b2j = b2[lane];

    // head fold: cls = [ sum_j alpha_j*ReLU(pre_j) > thrp ]
    float alpha, thrp;
    {
        const float wdj = w3[64 + lane] - w3[lane];
        const float c12 = g2[lane] * (1.0f / sqrtf(v2[lane] + kEps));
        const float c02 = be2[lane] - m2[lane] * c12;
        alpha = wdj * c12;
        const float C = lane_bcast(dpp_sum63(wdj * c02), 63);
        thrp = kLn3 - (b3[1] - b3[0]) - C;
    }

    // 8 swizzled row base indices for this lane's w2 row (float4 units).
    int wofs[8];
#pragma unroll
    for (int m = 0; m < 8; ++m) wofs[m] = lane * 32 + (m ^ (lane & 7));

    const float4* hu4 = reinterpret_cast<const float4*>(h1s[wiw][0]);
    const float4* hv4 = reinterpret_cast<const float4*>(h1s[wiw][1]);

    const int b0 = wid * bpw;
    const float* xb = x    + (size_t)b0 * 1024 + lane * 4;
    const float* mb = mask + (size_t)b0 * 4;
    float*       rp = out_ret + (size_t)b0 * 256 + lane * 4;
    float*       wp = out_w   + (size_t)b0 * 4;
    float*       cp = out_cls + b0;

    // ---- prologue: load pair 0 ----
    float4 xu0 = *reinterpret_cast<const float4*>(xb + 0);
    float4 xu1 = *reinterpret_cast<const float4*>(xb + 256);
    float4 xu2 = *reinterpret_cast<const float4*>(xb + 512);
    float4 xu3 = *reinterpret_cast<const float4*>(xb + 768);
    float4 xv0 = *reinterpret_cast<const float4*>(xb + 1024);
    float4 xv1 = *reinterpret_cast<const float4*>(xb + 1280);
    float4 xv2 = *reinterpret_cast<const float4*>(xb + 1536);
    float4 xv3 = *reinterpret_cast<const float4*>(xb + 1792);
    float4 mku = *reinterpret_cast<const float4*>(mb);
    float4 mkv = *reinterpret_cast<const float4*>(mb + 4);

#pragma unroll 1
    for (int i = 0; i < bpw; i += 2) {
        // Compiler barrier: stops LICM of the loop-invariant LDS w2 reads
        // (R3's spill hazard). Prefetch of this pair was issued before this
        // point (previous iteration), so overlap is preserved.
        asm volatile("" ::: "memory");

        // ---- phase 1: attention scores (8 independent DPP chains) ----
        float ru0 = dpp_sum63(dot4(xu0, aw));
        float ru1 = dpp_sum63(dot4(xu1, aw));
        float ru2 = dpp_sum63(dot4(xu2, aw));
        float ru3 = dpp_sum63(dot4(xu3, aw));
        float rv0 = dpp_sum63(dot4(xv0, aw));
        float rv1 = dpp_sum63(dot4(xv1, aw));
        float rv2 = dpp_sum63(dot4(xv2, aw));
        float rv3 = dpp_sum63(dot4(xv3, aw));
        const float au0 = fast_tanh(lane_bcast(ru0, 63) + ab) + mku.x;
        const float au1 = fast_tanh(lane_bcast(ru1, 63) + ab) + mku.y;
        const float au2 = fast_tanh(lane_bcast(ru2, 63) + ab) + mku.z;
        const float au3 = fast_tanh(lane_bcast(ru3, 63) + ab) + mku.w;
        const float av0 = fast_tanh(lane_bcast(rv0, 63) + ab) + mkv.x;
        const float av1 = fast_tanh(lane_bcast(rv1, 63) + ab) + mkv.y;
        const float av2 = fast_tanh(lane_bcast(rv2, 63) + ab) + mkv.z;
        const float av3 = fast_tanh(lane_bcast(rv3, 63) + ab) + mkv.w;

        // ---- softmax over 4 members, each batch ----
        const float umax = fmaxf(fmaxf(au0, au1), fmaxf(au2, au3));
        const float eu0 = __expf(au0 - umax), eu1 = __expf(au1 - umax);
        const float eu2 = __expf(au2 - umax), eu3 = __expf(au3 - umax);
        const float urs = __builtin_amdgcn_rcpf(((eu0 + eu1) + eu2) + eu3);
        const float wtu0 = eu0 * urs, wtu1 = eu1 * urs, wtu2 = eu2 * urs, wtu3 = eu3 * urs;

        const float vmax = fmaxf(fmaxf(av0, av1), fmaxf(av2, av3));
        const float ev0 = __expf(av0 - vmax), ev1 = __expf(av1 - vmax);
        const float ev2 = __expf(av2 - vmax), ev3 = __expf(av3 - vmax);
        const float vrs = __builtin_amdgcn_rcpf(((ev0 + ev1) + ev2) + ev3);
        const float wtv0 = ev0 * vrs, wtv1 = ev1 * vrs, wtv2 = ev2 * vrs, wtv3 = ev3 * vrs;

        // store attention weights now (kills their post-matvec liveness)
        if (lane == 0) {
            *reinterpret_cast<float4*>(wp + (size_t)i * 4) =
                make_float4(wtu0, wtu1, wtu2, wtu3);
            *reinterpret_cast<float4*>(wp + (size_t)(i + 1) * 4) =
                make_float4(wtv0, wtv1, wtv2, wtv3);
        }

        // ---- phase 2: pooling + gather candidates (x registers die here) ----
        float4 plU, gthU, plV, gthV;
        {
            int midx = 0; float mval = wtu0;
            if (wtu1 > mval) { mval = wtu1; midx = 1; }
            if (wtu2 > mval) { mval = wtu2; midx = 2; }
            if (wtu3 > mval) { mval = wtu3; midx = 3; }
            const float4 g01 = (midx == 1) ? xu1 : xu0;
            const float4 g23 = (midx == 3) ? xu3 : xu2;
            gthU = (midx >= 2) ? g23 : g01;
            plU.x = fmaf(wtu3, xu3.x, fmaf(wtu2, xu2.x, fmaf(wtu1, xu1.x, wtu0 * xu0.x)));
            plU.y = fmaf(wtu3, xu3.y, fmaf(wtu2, xu2.y, fmaf(wtu1, xu1.y, wtu0 * xu0.y)));
            plU.z = fmaf(wtu3, xu3.z, fmaf(wtu2, xu2.z, fmaf(wtu1, xu1.z, wtu0 * xu0.z)));
            plU.w = fmaf(wtu3, xu3.w, fmaf(wtu2, xu2.w, fmaf(wtu1, xu1.w, wtu0 * xu0.w)));
        }
        {
            int midx = 0; float mval = wtv0;
            if (wtv1 > mval) { mval = wtv1; midx = 1; }
            if (wtv2 > mval) { mval = wtv2; midx = 2; }
            if (wtv3 > mval) { mval = wtv3; midx = 3; }
            const float4 g01 = (midx == 1) ? xv1 : xv0;
            const float4 g23 = (midx == 3) ? xv3 : xv2;
            gthV = (midx >= 2) ? g23 : g01;
            plV.x = fmaf(wtv3, xv3.x, fmaf(wtv2, xv2.x, fmaf(wtv1, xv1.x, wtv0 * xv0.x)));
            plV.y = fmaf(wtv3, xv3.y, fmaf(wtv2, xv2.y, fmaf(wtv1, xv1.y, wtv0 * xv0.y)));
            plV.z = fmaf(wtv3, xv3.z, fmaf(wtv2, xv2.z, fmaf(wtv1, xv1.z, wtv0 * xv0.z)));
            plV.w = fmaf(wtv3, xv3.w, fmaf(wtv2, xv2.w, fmaf(wtv1, xv1.w, wtv0 * xv0.w)));
        }

        // ---- phase 3: prefetch next pair into the (now dead) x registers ----
        if (i + 2 < bpw) {
            const float* xn = xb + (size_t)(i + 2) * 1024;
            const float* mn = mb + (size_t)(i + 2) * 4;
            xu0 = *reinterpret_cast<const float4*>(xn + 0);
            xu1 = *reinterpret_cast<const float4*>(xn + 256);
            xu2 = *reinterpret_cast<const float4*>(xn + 512);
            xu3 = *reinterpret_cast<const float4*>(xn + 768);
            xv0 = *reinterpret_cast<const float4*>(xn + 1024);
            xv1 = *reinterpret_cast<const float4*>(xn + 1280);
            xv2 = *reinterpret_cast<const float4*>(xn + 1536);
            xv3 = *reinterpret_cast<const float4*>(xn + 1792);
            mku = *reinterpret_cast<const float4*>(mn);
            mkv = *reinterpret_cast<const float4*>(mn + 4);
        }

        // ---- phase 4: classifier ----
        float pu = fmaf(wtu3, w1a.w, fmaf(wtu2, w1a.z, fmaf(wtu1, w1a.y, wtu0 * w1a.x))) + b1a;
        const float h1uA = fmaf(fmaxf(pu, 0.0f), c1a, c0a);
        pu = fmaf(wtu3, w1b.w, fmaf(wtu2, w1b.z, fmaf(wtu1, w1b.y, wtu0 * w1b.x))) + b1b;
        const float h1uB = fmaf(fmaxf(pu, 0.0f), c1b, c0b);
        float pv = fmaf(wtv3, w1a.w, fmaf(wtv2, w1a.z, fmaf(wtv1, w1a.y, wtv0 * w1a.x))) + b1a;
        const float h1vA = fmaf(fmaxf(pv, 0.0f), c1a, c0a);
        pv = fmaf(wtv3, w1b.w, fmaf(wtv2, w1b.z, fmaf(wtv1, w1b.y, wtv0 * w1b.x))) + b1b;
        const float h1vB = fmaf(fmaxf(pv, 0.0f), c1b, c0b);

        // h1 broadcast via wave-private LDS row (uniform reads = broadcast,
        // conflict-free); replaces 512 v_readlane per pair.
        h1s[wiw][0][lane]      = h1uA;
        h1s[wiw][0][lane + 64] = h1uB;
        h1s[wiw][1][lane]      = h1vA;
        h1s[wiw][1][lane + 64] = h1vB;

        float accu0 = 0.0f, accu1 = 0.0f, accu2 = 0.0f, accu3 = 0.0f;
        float accv0 = 0.0f, accv1 = 0.0f, accv2 = 0.0f, accv3 = 0.0f;
#pragma unroll
        for (int c = 0; c < 32; ++c) {
            const float4 wv = w2s4[wofs[c & 7] + (c >> 3) * 8];
            const float4 hu = hu4[c];
            const float4 hv = hv4[c];
            accu0 = fmaf(hu.x, wv.x, accu0);
            accu1 = fmaf(hu.y, wv.y, accu1);
            accu2 = fmaf(hu.z, wv.z, accu2);
            accu3 = fmaf(hu.w, wv.w, accu3);
            accv0 = fmaf(hv.x, wv.x, accv0);
            accv1 = fmaf(hv.y, wv.y, accv1);
            accv2 = fmaf(hv.z, wv.z, accv2);
            accv3 = fmaf(hv.w, wv.w, accv3);
        }
        const float preU = ((accu0 + accu1) + (accu2 + accu3)) + b2j;
        const float preV = ((accv0 + accv1) + (accv2 + accv3)) + b2j;
        float dzu = dpp_sum63(alpha * fmaxf(preU, 0.0f));
        float dzv = dpp_sum63(alpha * fmaxf(preV, 0.0f));
        const int clsU = (lane_bcast(dzu, 63) > thrp) ? 1 : 0;
        const int clsV = (lane_bcast(dzv, 63) > thrp) ? 1 : 0;

        // ---- phase 5: select + store ----
        const float4 retU = (clsU == 1) ? gthU : plU;
        const float4 retV = (clsV == 1) ? gthV : plV;
        *reinterpret_cast<float4*>(rp + (size_t)i * 256)       = retU;
        *reinterpret_cast<float4*>(rp + (size_t)(i + 1) * 256) = retV;
        if (lane == 0) {
            cp[i]     = (float)clsU;
            cp[i + 1] = (float)clsV;
        }
    }
}

extern "C" void kernel_launch(void* const* d_in, const int* in_sizes, int n_in,
                              void* d_out, int out_size, void* d_ws, size_t ws_size,
                              hipStream_t stream) {
    const float* x      = (const float*)d_in[0];
    const float* mask   = (const float*)d_in[1];
    const float* attn_w = (const float*)d_in[2];
    const float* attn_b = (const float*)d_in[3];
    const float* w1     = (const float*)d_in[4];
    const float* b1     = (const float*)d_in[5];
    const float* g1     = (const float*)d_in[6];
    const float* be1    = (const float*)d_in[7];
    const float* m1     = (const float*)d_in[8];
    const float* v1     = (const float*)d_in[9];
    const float* w2     = (const float*)d_in[10];
    const float* b2     = (const float*)d_in[11];
    const float* g2     = (const float*)d_in[12];
    const float* be2    = (const float*)d_in[13];
    const float* m2     = (const float*)d_in[14];
    const float* v2     = (const float*)d_in[15];
    const float* w3     = (const float*)d_in[16];
    const float* b3     = (const float*)d_in[17];

    float* out = (float*)d_out;
    float* out_ret = out;                         // [B, 256]
    float* out_w   = out + (size_t)262144 * 256;  // [B, 4, 1]
    float* out_cls = out_w + (size_t)262144 * 4;  // [B]

    const int threads = 256;                      // 4 waves/block
    const int blocks  = 4096;                     // 16384 waves total
    const int waves   = blocks * (threads / 64);
    const int bpw     = 262144 / waves;           // 16 batches/wave (8 pairs)

    agg_fused<<<blocks, threads, 0, stream>>>(
        x, mask, attn_w, attn_b, w1, b1, g1, be1, m1, v1,
        w2, b2, g2, be2, m2, v2, w3, b3,
        out_ret, out_w, out_cls, bpw);
}

// Round 7
// 479.892 us; speedup vs baseline: 1.4361x; 1.3305x over previous
//
#include <hip/hip_runtime.h>
#include <hip/hip_bf16.h>

// AttentionAggregator: fused one-pass kernel, round 7.
// Strategy: stop fighting the register allocator (R3/R5/R6 all spilled at its
// 64-VGPR / 8-waves-per-EU target). Instead make the kernel GENUINELY fit:
//  - single-batch loop (x = 16 regs), w1/b1 in LDS, branch on wave-uniform cls
//    so pooled/gather are never both live  -> peak live ~56-60 VGPRs.
//  - w2 as bf16 pairs in LDS (16KB, XOR-swizzled) + w1/b1 (2.5KB) = 18.9KB
//    -> 8 blocks/CU -> 8 waves/EU real occupancy; TLP hides HBM latency with
//    NO explicit prefetch (the thing that kept triggering spills).
//  - bf16 w2 is numerics-safe: it feeds only the cls threshold test, which has
//    a >9 sigma margin (dz ~ N(0,0.107) vs thr ~ 1.0986); weight & ret paths
//    remain full f32.
//  - amdgpu_waves_per_eu(8,8) pins target = reality.
//  - loop-top asm"memory" clobber keeps LICM from hoisting the loop-invariant
//    LDS w2 tile into registers (R3's spill trigger).

namespace {
constexpr float kEps = 1e-5f;
constexpr float kLn3 = 1.0986122886681098f;  // ln(3)
}

__device__ __forceinline__ float lane_bcast(float v, int srclane) {
    return __uint_as_float(__builtin_amdgcn_readlane(__float_as_uint(v), srclane));
}

template <int CTRL>
__device__ __forceinline__ float dpp_add(float x) {
    int s = __builtin_amdgcn_update_dpp(0, __float_as_int(x), CTRL, 0xF, 0xF, true);
    return x + __int_as_float(s);
}

// Full 64-lane sum on the VALU pipe; total lands in lane 63.
__device__ __forceinline__ float dpp_sum63(float x) {
    x = dpp_add<0x111>(x);  // row_shr:1
    x = dpp_add<0x112>(x);  // row_shr:2
    x = dpp_add<0x114>(x);  // row_shr:4
    x = dpp_add<0x118>(x);  // row_shr:8
    x = dpp_add<0x142>(x);  // row_bcast:15
    x = dpp_add<0x143>(x);  // row_bcast:31
    return x;
}

__device__ __forceinline__ float dot4(float4 a, float4 b) {
    return fmaf(a.w, b.w, fmaf(a.z, b.z, fmaf(a.y, b.y, a.x * b.x)));
}

// tanh(x) = 1 - 2/(e^{2x}+1); ~1e-6 rel err, saturates correctly.
__device__ __forceinline__ float fast_tanh(float x) {
    const float t = __expf(2.0f * x);
    return fmaf(-2.0f, __builtin_amdgcn_rcpf(t + 1.0f), 1.0f);
}

__device__ __forceinline__ unsigned f2bf(float f) {  // round-to-nearest-even
    unsigned u = __float_as_uint(f);
    return (u + 0x7FFFu + ((u >> 16) & 1u)) >> 16;
}
__device__ __forceinline__ float bf_lo(unsigned d) {
    return __uint_as_float(d << 16);
}
__device__ __forceinline__ float bf_hi(unsigned d) {
    return __uint_as_float(d & 0xFFFF0000u);
}

__global__ __launch_bounds__(256)
__attribute__((amdgpu_waves_per_eu(8, 8)))
void agg_fused(
    const float* __restrict__ x, const float* __restrict__ mask,
    const float* __restrict__ attn_w, const float* __restrict__ attn_b,
    const float* __restrict__ w1, const float* __restrict__ b1,
    const float* __restrict__ g1, const float* __restrict__ be1,
    const float* __restrict__ m1, const float* __restrict__ v1,
    const float* __restrict__ w2, const float* __restrict__ b2,
    const float* __restrict__ g2, const float* __restrict__ be2,
    const float* __restrict__ m2, const float* __restrict__ v2,
    const float* __restrict__ w3, const float* __restrict__ b3,
    float* __restrict__ out_ret, float* __restrict__ out_w,
    float* __restrict__ out_cls, int bpw)
{
    // w2 as bf16 pairs (u32 words), swizzled: row j, chunk c (16B = 8 bf16)
    // stored at word index j*64 + (c ^ (j&15))*4 + q. A wave-wide b128 read of
    // chunk c across rows hits all 8 bank-groups -> structural minimum.
    __shared__ unsigned w2s[64 * 64];   // 16 KB
    __shared__ float    w1s[128 * 4];   // 2 KB
    __shared__ float    b1s[128];       // 0.5 KB

    const int tid  = threadIdx.x;
    const int lane = tid & 63;
    const int wid  = blockIdx.x * 4 + (tid >> 6);

    // ---- stage weights into LDS (once per block, coalesced) ----
    {
        const float2* w2v = reinterpret_cast<const float2*>(w2);
#pragma unroll
        for (int p = 0; p < 16; ++p) {
            const int i = tid + p * 256;          // float2 index = word index
            const float2 f = w2v[i];
            const int j = i >> 6, w = i & 63;
            const int c = w >> 2, q = w & 3;
            w2s[j * 64 + ((c ^ (j & 15)) << 2) + q] =
                f2bf(f.x) | (f2bf(f.y) << 16);
        }
        if (tid < 128) {
            b1s[tid] = b1[tid];
            const float4 r = *reinterpret_cast<const float4*>(w1 + tid * 4);
            *reinterpret_cast<float4*>(&w1s[tid * 4]) = r;
        }
    }
    __syncthreads();

    // ---- loop-invariant per-lane parameters (BN folded to fma consts) ----
    const float4 aw  = *reinterpret_cast<const float4*>(attn_w + lane * 4);
    const float  ab  = attn_b[0];
    const float  c1a = g1[lane] * (1.0f / sqrtf(v1[lane] + kEps));
    const float  c1b = g1[lane + 64] * (1.0f / sqrtf(v1[lane + 64] + kEps));
    const float  c0a = be1[lane] - m1[lane] * c1a;
    const float  c0b = be1[lane + 64] - m1[lane + 64] * c1b;
    const float  b2j = b2[lane];

    // head fold: cls = [ sum_j alpha_j*ReLU(pre_j) > thrp ]
    float alpha, thrp;
    {
        const float wdj = w3[64 + lane] - w3[lane];
        const float c12 = g2[lane] * (1.0f / sqrtf(v2[lane] + kEps));
        const float c02 = be2[lane] - m2[lane] * c12;
        alpha = wdj * c12;
        const float C = lane_bcast(dpp_sum63(wdj * c02), 63);
        thrp = kLn3 - (b3[1] - b3[0]) - C;
    }

    const unsigned* w2row = &w2s[lane * 64];
    const int swz = lane & 15;

    const int b0 = wid * bpw;
    const float* xp = x    + (size_t)b0 * 1024 + lane * 4;
    const float* mp = mask + (size_t)b0 * 4;
    float*       rp = out_ret + (size_t)b0 * 256 + lane * 4;
    float*       wp = out_w   + (size_t)b0 * 4;
    float*       cp = out_cls + b0;

#pragma unroll 1
    for (int i = 0; i < bpw; ++i) {
        // Keep LICM from hoisting the loop-invariant LDS w2/w1 reads into
        // registers (R3's spill trigger).
        asm volatile("" ::: "memory");

        // ---- load batch (4 coalesced b128 + uniform mask) ----
        const float4 x0 = *reinterpret_cast<const float4*>(xp + 0);
        const float4 x1 = *reinterpret_cast<const float4*>(xp + 256);
        const float4 x2 = *reinterpret_cast<const float4*>(xp + 512);
        const float4 x3 = *reinterpret_cast<const float4*>(xp + 768);
        const float4 mk = *reinterpret_cast<const float4*>(mp);

        // ---- attention scores: tanh(x . attn_w + b) + mask ----
        float r0 = dpp_sum63(dot4(x0, aw));
        float r1 = dpp_sum63(dot4(x1, aw));
        float r2 = dpp_sum63(dot4(x2, aw));
        float r3 = dpp_sum63(dot4(x3, aw));
        const float a0 = fast_tanh(lane_bcast(r0, 63) + ab) + mk.x;
        const float a1 = fast_tanh(lane_bcast(r1, 63) + ab) + mk.y;
        const float a2 = fast_tanh(lane_bcast(r2, 63) + ab) + mk.z;
        const float a3 = fast_tanh(lane_bcast(r3, 63) + ab) + mk.w;

        // ---- softmax over 4 members ----
        const float amax = fmaxf(fmaxf(a0, a1), fmaxf(a2, a3));
        const float e0 = __expf(a0 - amax), e1 = __expf(a1 - amax);
        const float e2 = __expf(a2 - amax), e3 = __expf(a3 - amax);
        const float rs = __builtin_amdgcn_rcpf(((e0 + e1) + e2) + e3);
        const float wt0 = e0 * rs, wt1 = e1 * rs, wt2 = e2 * rs, wt3 = e3 * rs;

        if (lane == 0)
            *reinterpret_cast<float4*>(wp + (size_t)i * 4) =
                make_float4(wt0, wt1, wt2, wt3);

        // ---- layer 1 (w1 rows from LDS): h1 = fma(relu(wf.row + b1), c1, c0) ----
        const float4 wr1 = *reinterpret_cast<const float4*>(&w1s[lane * 4]);
        const float4 wr2 = *reinterpret_cast<const float4*>(&w1s[(lane + 64) * 4]);
        float pre = fmaf(wt3, wr1.w, fmaf(wt2, wr1.z, fmaf(wt1, wr1.y, wt0 * wr1.x))) + b1s[lane];
        const float h1A = fmaf(fmaxf(pre, 0.0f), c1a, c0a);
        pre = fmaf(wt3, wr2.w, fmaf(wt2, wr2.z, fmaf(wt1, wr2.y, wt0 * wr2.x))) + b1s[lane + 64];
        const float h1B = fmaf(fmaxf(pre, 0.0f), c1b, c0b);

        // ---- layer 2 matvec: h2[lane] = h1 . w2[lane,:]; w2 bf16 from LDS,
        // h1 broadcast via v_readlane (imm lane indices, unrolled) ----
        float acc0 = 0.0f, acc1 = 0.0f, acc2 = 0.0f, acc3 = 0.0f;
#pragma unroll
        for (int c = 0; c < 16; ++c) {
            const uint4 d = *reinterpret_cast<const uint4*>(&w2row[((c ^ swz) << 2)]);
            const float hsrc = (c < 8) ? h1A : h1B;
            const int l0 = (8 * c) & 63;
            acc0 = fmaf(lane_bcast(hsrc, l0 + 0), bf_lo(d.x), acc0);
            acc1 = fmaf(lane_bcast(hsrc, l0 + 1), bf_hi(d.x), acc1);
            acc2 = fmaf(lane_bcast(hsrc, l0 + 2), bf_lo(d.y), acc2);
            acc3 = fmaf(lane_bcast(hsrc, l0 + 3), bf_hi(d.y), acc3);
            acc0 = fmaf(lane_bcast(hsrc, l0 + 4), bf_lo(d.z), acc0);
            acc1 = fmaf(lane_bcast(hsrc, l0 + 5), bf_hi(d.z), acc1);
            acc2 = fmaf(lane_bcast(hsrc, l0 + 6), bf_lo(d.w), acc2);
            acc3 = fmaf(lane_bcast(hsrc, l0 + 7), bf_hi(d.w), acc3);
        }
        const float h2pre = ((acc0 + acc1) + (acc2 + acc3)) + b2j;
        float dz = dpp_sum63(alpha * fmaxf(h2pre, 0.0f));
        const int cls = (lane_bcast(dz, 63) > thrp) ? 1 : 0;
        if (lane == 0) cp[i] = (float)cls;

        // ---- conditional pooling; cls is wave-uniform -> branch, so the
        // gather path and pooled path are never both live ----
        if (cls == 1) {
            int midx = 0; float mval = wt0;
            if (wt1 > mval) { mval = wt1; midx = 1; }
            if (wt2 > mval) { mval = wt2; midx = 2; }
            if (wt3 > mval) { mval = wt3; midx = 3; }
            const float4 g01 = (midx == 1) ? x1 : x0;
            const float4 g23 = (midx == 3) ? x3 : x2;
            const float4 gth = (midx >= 2) ? g23 : g01;
            *reinterpret_cast<float4*>(rp + (size_t)i * 256) = gth;
        } else {
            float4 pl;
            pl.x = fmaf(wt3, x3.x, fmaf(wt2, x2.x, fmaf(wt1, x1.x, wt0 * x0.x)));
            pl.y = fmaf(wt3, x3.y, fmaf(wt2, x2.y, fmaf(wt1, x1.y, wt0 * x0.y)));
            pl.z = fmaf(wt3, x3.z, fmaf(wt2, x2.z, fmaf(wt1, x1.z, wt0 * x0.z)));
            pl.w = fmaf(wt3, x3.w, fmaf(wt2, x2.w, fmaf(wt1, x1.w, wt0 * x0.w)));
            *reinterpret_cast<float4*>(rp + (size_t)i * 256) = pl;
        }

        xp += 1024;
        mp += 4;
    }
}

extern "C" void kernel_launch(void* const* d_in, const int* in_sizes, int n_in,
                              void* d_out, int out_size, void* d_ws, size_t ws_size,
                              hipStream_t stream) {
    const float* x      = (const float*)d_in[0];
    const float* mask   = (const float*)d_in[1];
    const float* attn_w = (const float*)d_in[2];
    const float* attn_b = (const float*)d_in[3];
    const float* w1     = (const float*)d_in[4];
    const float* b1     = (const float*)d_in[5];
    const float* g1     = (const float*)d_in[6];
    const float* be1    = (const float*)d_in[7];
    const float* m1     = (const float*)d_in[8];
    const float* v1     = (const float*)d_in[9];
    const float* w2     = (const float*)d_in[10];
    const float* b2     = (const float*)d_in[11];
    const float* g2     = (const float*)d_in[12];
    const float* be2    = (const float*)d_in[13];
    const float* m2     = (const float*)d_in[14];
    const float* v2     = (const float*)d_in[15];
    const float* w3     = (const float*)d_in[16];
    const float* b3     = (const float*)d_in[17];

    float* out = (float*)d_out;
    float* out_ret = out;                         // [B, 256]
    float* out_w   = out + (size_t)262144 * 256;  // [B, 4, 1]
    float* out_cls = out_w + (size_t)262144 * 4;  // [B]

    const int threads = 256;                      // 4 waves/block
    const int blocks  = 4096;                     // 16384 waves total
    const int waves   = blocks * (threads / 64);
    const int bpw     = 262144 / waves;           // 16 batches/wave

    agg_fused<<<blocks, threads, 0, stream>>>(
        x, mask, attn_w, attn_b, w1, b1, g1, be1, m1, v1,
        w2, b2, g2, be2, m2, v2, w3, b3,
        out_ret, out_w, out_cls, bpw);
}